// Round 13
// baseline (432.188 us; speedup 1.0000x reference)
//
#include <hip/hip_runtime.h>

#define NPTS 1048576
#define NBKT 262144  // 2^18 Morton buckets

typedef short bhalf8 __attribute__((ext_vector_type(8)));
typedef _Float16 halfv8 __attribute__((ext_vector_type(8)));
typedef _Float16 halfv2 __attribute__((ext_vector_type(2)));
typedef float floatx4 __attribute__((ext_vector_type(4)));

#define WSZ 24320  // f16 elements of weight storage
#define MLP_THREADS 512
#define MLP_WAVES 8
#define MLP_BLOCKS 1024
#define SCR_STR 80

// prep_kernel block ranges
#define PB_PLANES 16320  // 4177920 texels / 256
#define PB_HASH 4096
#define PB_HIST 4096

__device__ const float HRg[16] = {16.f, 19.f, 24.f, 30.f, 37.f, 46.f, 57.f, 71.f,
                                  89.f, 110.f, 136.f, 169.f, 210.f, 260.f, 322.f, 400.f};

// ---------------- helpers ----------------

__device__ __forceinline__ float my_tanh(float x) {
  float e = __expf(2.f * x);
  return 1.f - 2.f * __builtin_amdgcn_rcpf(e + 1.f);
}

__device__ __forceinline__ float my_sigmoid(float x) {
  return __builtin_amdgcn_rcpf(1.f + __expf(-x));
}

__device__ __forceinline__ unsigned short f2h(float v) {
  _Float16 h = (_Float16)v;
  unsigned short u;
  __builtin_memcpy(&u, &h, 2);
  return u;
}

__device__ __forceinline__ float h2f(unsigned short u) {
  _Float16 h;
  __builtin_memcpy(&h, &u, 2);
  return (float)h;
}

__device__ __forceinline__ float texch(uint2 t, int c) {
  unsigned short u = (c == 0) ? (unsigned short)(t.x & 0xffffu)
                   : (c == 1) ? (unsigned short)(t.x >> 16)
                              : (unsigned short)(t.y & 0xffffu);
  return h2f(u);
}

__device__ __forceinline__ unsigned mort6(unsigned x) {
  return (x & 1) | ((x & 2) << 2) | ((x & 4) << 4) |
         ((x & 8) << 6) | ((x & 16) << 8) | ((x & 32) << 10);
}

__device__ __forceinline__ unsigned morton_key(float px, float py, float pz) {
  float qx = (px + 4.f) * 0.125f, qy = (py + 4.f) * 0.125f, qz = (pz + 2.f) * 0.25f;
  unsigned kx = min(63, max(0, (int)(qx * 64.f)));
  unsigned ky = min(63, max(0, (int)(qy * 64.f)));
  unsigned kz = min(63, max(0, (int)(qz * 64.f)));
  return mort6(kx) | (mort6(ky) << 1) | (mort6(kz) << 2);
}

// ---------------- pipelined gather primitives ----------------

struct Raw {
  uint2 a00, a01, a10, a11;
  uint2 b00, b01, b10, b11;
  uint2 c00, c01, c10, c11;
  uint2 d00, d01, d10, d11;
  unsigned tv0[8], tv1[8], tv2[8], tv3[8];
};

__device__ __forceinline__ void plane_const(int s, int& R, int& m, unsigned& base) {
  int level = s / 3;
  m = s - 3 * level;
  R = 128 << level;
  base = 16384u * ((1u << (2 * level)) - 1u) + (unsigned)m * (unsigned)(R * R);
}

__device__ __forceinline__ void plane_iss(const uint2* __restrict__ planes, int R,
                                          unsigned base, int m, float u, float v, float w,
                                          uint2& t00, uint2& t01, uint2& t10, uint2& t11) {
  const float a = (m == 2) ? v : u;
  const float b = (m == 0) ? v : w;
  const float Rm1 = (float)(R - 1);
  float x = fminf(fmaxf((a + 1.f) * 0.5f * Rm1, 0.f), Rm1);
  float y = fminf(fmaxf((b + 1.f) * 0.5f * Rm1, 0.f), Rm1);
  int x0 = (int)x, y0 = (int)y;
  int x1 = min(x0 + 1, R - 1), y1 = min(y0 + 1, R - 1);
  t00 = planes[base + y0 * R + x0];
  t01 = planes[base + y0 * R + x1];
  t10 = planes[base + y1 * R + x0];
  t11 = planes[base + y1 * R + x1];
}

__device__ __forceinline__ uint2 plane_fin(int R, int m, float u, float v, float w,
                                           uint2 t00, uint2 t01, uint2 t10, uint2 t11) {
  const float a = (m == 2) ? v : u;
  const float b = (m == 0) ? v : w;
  const float Rm1 = (float)(R - 1);
  float x = fminf(fmaxf((a + 1.f) * 0.5f * Rm1, 0.f), Rm1);
  float y = fminf(fmaxf((b + 1.f) * 0.5f * Rm1, 0.f), Rm1);
  float wx = x - floorf(x), wy = y - floorf(y);
  _Float16 h00 = (_Float16)((1.f - wy) * (1.f - wx));
  _Float16 h01 = (_Float16)((1.f - wy) * wx);
  _Float16 h10 = (_Float16)(wy * (1.f - wx));
  _Float16 h11 = (_Float16)(wy * wx);
  halfv2 w00 = {h00, h00}, w01 = {h01, h01}, w10 = {h10, h10}, w11 = {h11, h11};
  halfv2 l00, l01, l10, l11, u00, u01, u10, u11;
  __builtin_memcpy(&l00, &t00.x, 4); __builtin_memcpy(&u00, &t00.y, 4);
  __builtin_memcpy(&l01, &t01.x, 4); __builtin_memcpy(&u01, &t01.y, 4);
  __builtin_memcpy(&l10, &t10.x, 4); __builtin_memcpy(&u10, &t10.y, 4);
  __builtin_memcpy(&l11, &t11.x, 4); __builtin_memcpy(&u11, &t11.y, 4);
  halfv2 alo = l00 * w00 + l01 * w01 + l10 * w10 + l11 * w11;
  halfv2 ahi = u00 * w00 + u01 * w01 + u10 * w10 + u11 * w11;
  uint2 r;
  __builtin_memcpy(&r.x, &alo, 4);
  __builtin_memcpy(&r.y, &ahi, 4);
  return r;
}

__device__ __forceinline__ void hash_iss(const unsigned* __restrict__ hb, float r,
                                         float q0, float q1, float q2, unsigned (&tv)[8]) {
  float x0 = q0 * r, x1 = q1 * r, x2 = q2 * r;
  unsigned i0 = (unsigned)(int)floorf(x0);
  unsigned i1 = (unsigned)(int)floorf(x1);
  unsigned i2 = (unsigned)(int)floorf(x2);
#pragma unroll
  for (int dz = 0; dz < 2; ++dz)
#pragma unroll
    for (int dy = 0; dy < 2; ++dy)
#pragma unroll
      for (int dx = 0; dx < 2; ++dx) {
        unsigned h = (i0 + dx) ^ ((i1 + dy) * 2654435761u) ^ ((i2 + dz) * 805459861u);
        tv[dz * 4 + dy * 2 + dx] = hb[h & 65535u];
      }
}

__device__ __forceinline__ unsigned hash_fin(float r, float q0, float q1, float q2,
                                             const unsigned (&tv)[8]) {
  float x0 = q0 * r, x1 = q1 * r, x2 = q2 * r;
  float w0 = x0 - floorf(x0), w1 = x1 - floorf(x1), w2 = x2 - floorf(x2);
  halfv2 acc2 = {(_Float16)0.f, (_Float16)0.f};
#pragma unroll
  for (int c = 0; c < 8; ++c) {
    const int dx = c & 1, dy = (c >> 1) & 1, dz = c >> 2;
    float wgt = (dx ? w0 : 1.f - w0) * (dy ? w1 : 1.f - w1) * (dz ? w2 : 1.f - w2);
    halfv2 th;
    __builtin_memcpy(&th, &tv[c], 4);
    _Float16 wh = (_Float16)wgt;
    halfv2 w2v = {wh, wh};
    acc2 = th * w2v + acc2;
  }
  unsigned res;
  __builtin_memcpy(&res, &acc2, 4);
  return res;
}

// ---------------- fused prep kernel ----------------

struct PrepParams {
  const float* psrc[12];
  ushort4* pdst[12];
  const float* hash;
  unsigned* hashb;
  const float* p;
  unsigned* hist;
};

__global__ __launch_bounds__(256) void prep_kernel(PrepParams P) {
  const int b = blockIdx.x;
  if (b < PB_PLANES) {
    const int CUM[13] = {0, 16384, 32768, 49152, 114688, 180224, 245760,
                         507904, 770048, 1032192, 2080768, 3129344, 4177920};
    const int RESL[12] = {128, 128, 128, 256, 256, 256, 512, 512, 512, 1024, 1024, 1024};
    const int s = b << 8;
    int pi = 0;
#pragma unroll
    for (int i = 1; i < 12; ++i)
      if (s >= CUM[i]) pi = i;
    const int li = s + threadIdx.x - CUM[pi];
    const int R = RESL[pi];
    const int n = R * R;
    const float* __restrict__ src = P.psrc[pi];
    ushort4 t;
    t.x = f2h(src[li]);
    t.y = f2h(src[n + li]);
    t.z = f2h(src[2 * n + li]);
    t.w = 0;
    P.pdst[pi][li] = t;
  } else if (b < PB_PLANES + PB_HASH) {
    const int i = ((b - PB_PLANES) << 8) + threadIdx.x;
    float2 v = *(const float2*)(P.hash + (size_t)i * 2);
    P.hashb[i] = (unsigned)f2h(v.x) | ((unsigned)f2h(v.y) << 16);
  } else {
    const int i = ((b - PB_PLANES - PB_HASH) << 8) + threadIdx.x;
    const float* pp = P.p + (size_t)i * 3;
    unsigned k = morton_key(pp[0], pp[1], pp[2]);
    atomicAdd(&P.hist[k], 1u);
  }
}

// ---------------- hierarchical scan ----------------

__global__ __launch_bounds__(256) void scan1_kernel(const unsigned* __restrict__ hist,
                                                    unsigned* __restrict__ partial) {
  __shared__ unsigned s[256];
  const int b = blockIdx.x, t = threadIdx.x;
  uint4 v = ((const uint4*)(hist + b * 1024))[t];
  s[t] = v.x + v.y + v.z + v.w;
  __syncthreads();
  for (int d = 128; d > 0; d >>= 1) {
    if (t < d) s[t] += s[t + d];
    __syncthreads();
  }
  if (t == 0) partial[b] = s[0];
}

__global__ __launch_bounds__(256) void scan2_kernel(const unsigned* __restrict__ partial,
                                                    unsigned* __restrict__ base) {
  __shared__ unsigned s[256];
  const int t = threadIdx.x;
  s[t] = partial[t];
  __syncthreads();
  for (int d = 1; d < 256; d <<= 1) {
    unsigned v = (t >= d) ? s[t - d] : 0u;
    __syncthreads();
    s[t] += v;
    __syncthreads();
  }
  base[t] = (t == 0) ? 0u : s[t - 1];
}

__global__ __launch_bounds__(256) void scan3_kernel(const unsigned* __restrict__ hist,
                                                    const unsigned* __restrict__ base,
                                                    unsigned* __restrict__ cursor) {
  __shared__ unsigned s[256];
  const int b = blockIdx.x, t = threadIdx.x;
  uint4 v = ((const uint4*)(hist + b * 1024))[t];
  unsigned sum = v.x + v.y + v.z + v.w;
  s[t] = sum;
  __syncthreads();
  for (int d = 1; d < 256; d <<= 1) {
    unsigned x = (t >= d) ? s[t - d] : 0u;
    __syncthreads();
    s[t] += x;
    __syncthreads();
  }
  unsigned off = base[b] + s[t] - sum;
  uint4 c;
  c.x = off;
  c.y = off + v.x;
  c.z = off + v.x + v.y;
  c.w = off + v.x + v.y + v.z;
  ((uint4*)(cursor + b * 1024))[t] = c;
}

__global__ __launch_bounds__(256) void scatter_kernel(const float* __restrict__ p,
                                                      unsigned* __restrict__ cursor,
                                                      float4* __restrict__ qs) {
  int i = blockIdx.x * 256 + threadIdx.x;
  const float* pp = p + (size_t)i * 3;
  const float px = pp[0], py = pp[1], pz = pp[2];
  unsigned k = morton_key(px, py, pz);
  unsigned slot = atomicAdd(&cursor[k], 1u);
  float4 q;
  q.x = (px + 4.f) * 0.125f;
  q.y = (py + 4.f) * 0.125f;
  q.z = (pz + 2.f) * 0.25f;
  q.w = __uint_as_float((unsigned)i);
  qs[slot] = q;
}

// ---------------- repack kernel (fallback only) ----------------

__global__ __launch_bounds__(256) void repack_plane(const float* __restrict__ src,
                                                    ushort4* __restrict__ dst, int R) {
  int i = blockIdx.x * 256 + threadIdx.x;
  int n = R * R;
  if (i >= n) return;
  ushort4 t;
  t.x = f2h(src[i]);
  t.y = f2h(src[n + i]);
  t.z = f2h(src[2 * n + i]);
  t.w = 0;
  dst[i] = t;
}

// ---------------- plane samplers (fallback) ----------------

__device__ __forceinline__ void sample3i(const uint2* __restrict__ pl,
                                         float a, float b, int R, float* f) {
  const float Rm1 = (float)(R - 1);
  float x = fminf(fmaxf((a + 1.f) * 0.5f * Rm1, 0.f), Rm1);
  float y = fminf(fmaxf((b + 1.f) * 0.5f * Rm1, 0.f), Rm1);
  float x0f = floorf(x), y0f = floorf(y);
  float wx = x - x0f, wy = y - y0f;
  int x0 = (int)x0f, y0 = (int)y0f;
  int x1 = min(x0 + 1, R - 1), y1 = min(y0 + 1, R - 1);
  float w00 = (1.f - wy) * (1.f - wx);
  float w01 = (1.f - wy) * wx;
  float w10 = wy * (1.f - wx);
  float w11 = wy * wx;
  uint2 t00 = pl[y0 * R + x0];
  uint2 t01 = pl[y0 * R + x1];
  uint2 t10 = pl[y1 * R + x0];
  uint2 t11 = pl[y1 * R + x1];
#pragma unroll
  for (int c = 0; c < 3; ++c) {
    f[c] = texch(t00, c) * w00 + texch(t01, c) * w01 +
           texch(t10, c) * w10 + texch(t11, c) * w11;
  }
}

__device__ __forceinline__ void sample3f(const float* __restrict__ pl,
                                         float a, float b, int R, float* f) {
  const float Rm1 = (float)(R - 1);
  float x = fminf(fmaxf((a + 1.f) * 0.5f * Rm1, 0.f), Rm1);
  float y = fminf(fmaxf((b + 1.f) * 0.5f * Rm1, 0.f), Rm1);
  float x0f = floorf(x), y0f = floorf(y);
  float wx = x - x0f, wy = y - y0f;
  int x0 = (int)x0f, y0 = (int)y0f;
  int x1 = min(x0 + 1, R - 1), y1 = min(y0 + 1, R - 1);
  float w00 = (1.f - wy) * (1.f - wx);
  float w01 = (1.f - wy) * wx;
  float w10 = wy * (1.f - wx);
  float w11 = wy * wx;
  int i00 = y0 * R + x0, i01 = y0 * R + x1;
  int i10 = y1 * R + x0, i11 = y1 * R + x1;
  const int R2 = R * R;
#pragma unroll
  for (int c = 0; c < 3; ++c) {
    const float* base = pl + c * R2;
    f[c] = base[i00] * w00 + base[i01] * w01 + base[i10] * w10 + base[i11] * w11;
  }
}

// ---------------- fused MFMA kernel (pipelined gathers) ----------------

struct MlpWParams {
  const uint2* planes;
  const unsigned* hashb;
  const float4* qs;
  const float* W0; const float* b0;
  const float* W1; const float* b1;
  const float* Wo; const float* bo;
  const float* Wc0; const float* bc0;
  const float* Wc1; const float* bc1;
  const float* Wco; const float* bco;
  float* out;
};

// MODE 0: W0 (planes padded + hash); MODE 1: Wc0 (geo + planes padded); MODE 2: direct
template <int MODE>
__device__ __forceinline__ void stage_w(const float* __restrict__ src, int K, int Nsrc,
                                        int STR, int NPAD, int OFF, short* Wlds, int tid) {
  const int total = NPAD * STR;
  for (int idx = tid; idx < total; idx += MLP_THREADS) {
    int c = idx / STR;
    int kp = idx - c * STR;
    int sk = -1;
    if (MODE == 0) {
      if (kp < 48) {
        int s = kp >> 2, ch = kp & 3;
        if (ch < 3) sk = s * 3 + ch;
      } else if (kp < 80) {
        sk = 36 + (kp - 48);
      }
    } else if (MODE == 1) {
      if (kp < 32) {
        sk = kp;
      } else if (kp < 80) {
        int s = (kp - 32) >> 2, ch = (kp - 32) & 3;
        if (ch < 3) sk = 32 + s * 3 + ch;
      }
    } else {
      if (kp < K) sk = kp;
    }
    float val = (sk >= 0 && c < Nsrc) ? src[sk * Nsrc + c] : 0.f;
    Wlds[OFF + idx] = (short)f2h(val);
  }
}

__device__ __forceinline__ void stage_b(const float* __restrict__ src, int Nsrc, int NPAD,
                                        int BOFF, float* Blds, int tid) {
  for (int j = tid; j < NPAD; j += MLP_THREADS) Blds[BOFF + j] = (j < Nsrc) ? src[j] : 0.f;
}

__device__ __forceinline__ halfv8 as_h8(bhalf8 s) {
  halfv8 h;
  __builtin_memcpy(&h, &s, 16);
  return h;
}

__device__ __forceinline__ halfv8 frag4(unsigned d0, unsigned d1, unsigned d2, unsigned d3) {
  bhalf8 r;
  r[0] = (short)(d0 & 0xffffu); r[1] = (short)(d0 >> 16);
  r[2] = (short)(d1 & 0xffffu); r[3] = (short)(d1 >> 16);
  r[4] = (short)(d2 & 0xffffu); r[5] = (short)(d2 >> 16);
  r[6] = (short)(d3 & 0xffffu); r[7] = (short)(d3 >> 16);
  return as_h8(r);
}

__device__ __forceinline__ halfv8 ldS(const short* scr, int rowl, int grp, int s) {
  return *(const halfv8*)&scr[rowl * SCR_STR + 32 * s + 8 * grp];
}

template <int NT, int KS, int OFF, int STR>
__device__ __forceinline__ void mlayer(const halfv8 (&af)[KS], floatx4 (&acc)[NT],
                                       const short* Wlds, int rowl, int grp) {
#pragma unroll
  for (int n = 0; n < NT; ++n) {
    floatx4 a{};
#pragma unroll
    for (int s = 0; s < KS; ++s) {
      const int wo = OFF + (16 * n + rowl) * STR + 32 * s + 8 * grp;
      const halfv8 wA = *(const halfv8*)&Wlds[wo];
      a = __builtin_amdgcn_mfma_f32_16x16x32_f16(wA, af[s], a, 0, 0, 0);
    }
    acc[n] = a;
  }
}

template <int NT>
__device__ __forceinline__ void relu_wr(const floatx4 (&acc)[NT], const float* Blds,
                                        int boff, short* scr, int rowl, int grp) {
#pragma unroll
  for (int n = 0; n < NT; ++n) {
    const int cbase = 16 * n + 4 * grp;
    short4 v4;
    float v0 = fmaxf(acc[n][0] + Blds[boff + cbase + 0], 0.f);
    float v1 = fmaxf(acc[n][1] + Blds[boff + cbase + 1], 0.f);
    float v2 = fmaxf(acc[n][2] + Blds[boff + cbase + 2], 0.f);
    float v3 = fmaxf(acc[n][3] + Blds[boff + cbase + 3], 0.f);
    v4.x = (short)f2h(v0);
    v4.y = (short)f2h(v1);
    v4.z = (short)f2h(v2);
    v4.w = (short)f2h(v3);
    *(short4*)&scr[rowl * SCR_STR + cbase] = v4;
  }
}

__device__ __forceinline__ void tanh_wr(const floatx4 (&acc)[3], const float* Blds,
                                        short* scr, float* ost, int rowl, int grp) {
#pragma unroll
  for (int n = 0; n < 3; ++n) {
#pragma unroll
    for (int r = 0; r < 4; ++r) {
      const int c = 16 * n + 4 * grp + r;
      float v = my_tanh(acc[n][r] + Blds[128 + c]);
      if (c == 0) ost[rowl * 4 + 3] = v;
      if (c >= 1 && c <= 32) scr[rowl * SCR_STR + c - 1] = (short)f2h(v);
    }
  }
}

__global__ __launch_bounds__(MLP_THREADS, 2) void mlp_fused(MlpWParams P) {
  __shared__ short Wlds[WSZ];                       // 48,640 B
  __shared__ float Blds[288];                       //  1,152 B
  __shared__ short Scr[MLP_WAVES * 16 * SCR_STR];   // 20,480 B
  __shared__ float Ost[MLP_WAVES][16][4];           //  2,048 B

  const int tid = threadIdx.x;

  stage_w<0>(P.W0,  96, 64, 104, 64,     0, Wlds, tid);
  stage_w<2>(P.W1,  64, 64,  72, 64,  6656, Wlds, tid);
  stage_w<2>(P.Wo,  64, 33,  72, 48, 11264, Wlds, tid);
  stage_w<1>(P.Wc0, 96, 64, 104, 64, 14720, Wlds, tid);
  stage_w<2>(P.Wc1, 64, 32,  72, 32, 21376, Wlds, tid);
  stage_w<2>(P.Wco, 32,  3,  40, 16, 23680, Wlds, tid);
  stage_b(P.b0,  64, 64,   0, Blds, tid);
  stage_b(P.b1,  64, 64,  64, Blds, tid);
  stage_b(P.bo,  33, 48, 128, Blds, tid);
  stage_b(P.bc0, 64, 64, 176, Blds, tid);
  stage_b(P.bc1, 32, 32, 240, Blds, tid);
  stage_b(P.bco,  3, 16, 272, Blds, tid);
  __syncthreads();

  const int wave = tid >> 6, lane = tid & 63;
  const int rowl = lane & 15, grp = lane >> 4;
  short* scr0 = &Scr[wave * 16 * SCR_STR];
  float* ost0 = &Ost[wave][0][0];

  int bid = blockIdx.x;
  bid = (bid & 7) * (MLP_BLOCKS / 8) + (bid >> 3);

  // hoisted per-lane sample constants
  const int s0 = 2 * grp, s1 = 2 * grp + 1;
  const int s2 = 8 + 2 * grp, s3 = 9 + 2 * grp;  // used only for grp<2
  int R0, m0, R1, m1, R2, m2, R3, m3;
  unsigned B0, B1, B2, B3;
  plane_const(s0, R0, m0, B0);
  plane_const(s1, R1, m1, B1);
  plane_const(s2, R2, m2, B2);
  plane_const(s3, R3, m3, B3);
  const int lbase = (grp < 2) ? (8 + 4 * grp) : (4 * grp - 8);
  const unsigned* hb0 = P.hashb + ((unsigned)(lbase + 0) << 16);
  const unsigned* hb1 = P.hashb + ((unsigned)(lbase + 1) << 16);
  const unsigned* hb2 = P.hashb + ((unsigned)(lbase + 2) << 16);
  const unsigned* hb3 = P.hashb + ((unsigned)(lbase + 3) << 16);
  const float hr0 = HRg[lbase + 0], hr1 = HRg[lbase + 1];
  const float hr2 = HRg[lbase + 2], hr3 = HRg[lbase + 3];

  auto issue = [&](const float4& q4, Raw& r) {
    const float q0 = q4.x, q1 = q4.y, q2 = q4.z;
    const float uu = 2.f * q0 - 1.f, vv = 2.f * q1 - 1.f, ww = 2.f * q2 - 1.f;
    plane_iss(P.planes, R0, B0, m0, uu, vv, ww, r.a00, r.a01, r.a10, r.a11);
    plane_iss(P.planes, R1, B1, m1, uu, vv, ww, r.b00, r.b01, r.b10, r.b11);
    if (grp < 2) {
      plane_iss(P.planes, R2, B2, m2, uu, vv, ww, r.c00, r.c01, r.c10, r.c11);
      plane_iss(P.planes, R3, B3, m3, uu, vv, ww, r.d00, r.d01, r.d10, r.d11);
    }
    hash_iss(hb0, hr0, q0, q1, q2, r.tv0);
    hash_iss(hb1, hr1, q0, q1, q2, r.tv1);
    hash_iss(hb2, hr2, q0, q1, q2, r.tv2);
    hash_iss(hb3, hr3, q0, q1, q2, r.tv3);
  };

  auto body = [&](int t, Raw& cur, Raw& nxt, const float4& qcur, float4& qnxt) {
    // prefetch next q (latency hidden under interp below)
    if (t < 7) qnxt = P.qs[((bid * 8 + (t + 1)) * MLP_WAVES + wave) * 16 + rowl];

    // finish current gathers -> fragments
    const float q0 = qcur.x, q1 = qcur.y, q2 = qcur.z;
    const unsigned pid = __float_as_uint(qcur.w);
    const float uu = 2.f * q0 - 1.f, vv = 2.f * q1 - 1.f, ww = 2.f * q2 - 1.f;
    uint2 sA = plane_fin(R0, m0, uu, vv, ww, cur.a00, cur.a01, cur.a10, cur.a11);
    uint2 sB = plane_fin(R1, m1, uu, vv, ww, cur.b00, cur.b01, cur.b10, cur.b11);
    uint2 sC = {0u, 0u}, sD = {0u, 0u};
    if (grp < 2) {
      sC = plane_fin(R2, m2, uu, vv, ww, cur.c00, cur.c01, cur.c10, cur.c11);
      sD = plane_fin(R3, m3, uu, vv, ww, cur.d00, cur.d01, cur.d10, cur.d11);
    }
    unsigned h0 = hash_fin(hr0, q0, q1, q2, cur.tv0);
    unsigned h1 = hash_fin(hr1, q0, q1, q2, cur.tv1);
    unsigned h2 = hash_fin(hr2, q0, q1, q2, cur.tv2);
    unsigned h3 = hash_fin(hr3, q0, q1, q2, cur.tv3);

    halfv8 af0 = frag4(sA.x, sA.y, sB.x, sB.y);
    halfv8 af1 = (grp < 2) ? frag4(sC.x, sC.y, sD.x, sD.y) : frag4(h0, h1, h2, h3);
    halfv8 af2 = (grp < 2) ? frag4(h0, h1, h2, h3) : frag4(0u, 0u, 0u, 0u);
    halfv8 zf = frag4(0u, 0u, 0u, 0u);

    // issue next gathers (results consumed next iteration, after full MLP)
    if (t < 7) issue(qnxt, nxt);

    // ---- MLP ----
    {
      halfv8 afA[3] = {af0, af1, af2};
      floatx4 accA[4];
      mlayer<4, 3, 0, 104>(afA, accA, Wlds, rowl, grp);
      relu_wr<4>(accA, Blds, 0, scr0, rowl, grp);
    }
    {
      halfv8 afA[2] = {ldS(scr0, rowl, grp, 0), ldS(scr0, rowl, grp, 1)};
      floatx4 accA[4];
      mlayer<4, 2, 6656, 72>(afA, accA, Wlds, rowl, grp);
      relu_wr<4>(accA, Blds, 64, scr0, rowl, grp);
    }
    {
      halfv8 afA[2] = {ldS(scr0, rowl, grp, 0), ldS(scr0, rowl, grp, 1)};
      floatx4 accA[3];
      mlayer<3, 2, 11264, 72>(afA, accA, Wlds, rowl, grp);
      tanh_wr(accA, Blds, scr0, ost0, rowl, grp);
    }
    {
      halfv8 afA[3] = {ldS(scr0, rowl, grp, 0), af0, (grp < 2) ? af1 : zf};
      floatx4 accA[4];
      mlayer<4, 3, 14720, 104>(afA, accA, Wlds, rowl, grp);
      relu_wr<4>(accA, Blds, 176, scr0, rowl, grp);
    }
    {
      halfv8 afA[2] = {ldS(scr0, rowl, grp, 0), ldS(scr0, rowl, grp, 1)};
      floatx4 accA[2];
      mlayer<2, 2, 21376, 72>(afA, accA, Wlds, rowl, grp);
      relu_wr<2>(accA, Blds, 240, scr0, rowl, grp);
    }
    {
      halfv8 afA[1] = {ldS(scr0, rowl, grp, 0)};
      floatx4 accA[1];
      mlayer<1, 1, 23680, 40>(afA, accA, Wlds, rowl, grp);
#pragma unroll
      for (int r = 0; r < 4; ++r) {
        const int c = 4 * grp + r;
        if (c < 3) {
          float vA = my_sigmoid(accA[0][r] + Blds[272 + c]);
          ost0[rowl * 4 + c] = vA;
        }
      }
    }

    if (lane < 16) {
      float4 o = *(float4*)&Ost[wave][lane][0];
      ((float4*)P.out)[pid] = o;
    }
  };

  Raw rA, rB;
  float4 qA, qB;
  qA = P.qs[((bid * 8 + 0) * MLP_WAVES + wave) * 16 + rowl];
  issue(qA, rA);

  for (int tt = 0; tt < 4; ++tt) {
    body(2 * tt, rA, rB, qA, qB);
    body(2 * tt + 1, rB, rA, qB, qA);
  }
}

// ---------------- fused fallback (scalar f16 kernel) ----------------

struct DecParams {
  const float* p;
  const float* pl[12];
  const uint2* pli[12];
  const float* hash;
  const float* W0; const float* b0;
  const float* W1; const float* b1;
  const float* Wo; const float* bo;
  const float* Wc0; const float* bc0;
  const float* Wc1; const float* bc1;
  const float* Wco; const float* bco;
  float* out;
};

template <bool ILV>
__global__ __launch_bounds__(256) void dec_kernel(DecParams P) {
  const int tid = blockIdx.x * 256 + threadIdx.x;

  const float* __restrict__ pp = P.p + (size_t)tid * 3;
  const float px = pp[0], py = pp[1], pz = pp[2];

  const float u = (px + 4.f) * 0.25f - 1.f;
  const float v = (py + 4.f) * 0.25f - 1.f;
  const float w = (pz + 2.f) * 0.5f - 1.f;

  float feat[68];
  {
    const int RES[4] = {128, 256, 512, 1024};
#pragma unroll
    for (int li = 0; li < 4; ++li) {
      if (ILV) {
        sample3i(P.pli[li * 3 + 0], u, v, RES[li], &feat[li * 9 + 0]);
        sample3i(P.pli[li * 3 + 1], u, w, RES[li], &feat[li * 9 + 3]);
        sample3i(P.pli[li * 3 + 2], v, w, RES[li], &feat[li * 9 + 6]);
      } else {
        sample3f(P.pl[li * 3 + 0], u, v, RES[li], &feat[li * 9 + 0]);
        sample3f(P.pl[li * 3 + 1], u, w, RES[li], &feat[li * 9 + 3]);
        sample3f(P.pl[li * 3 + 2], v, w, RES[li], &feat[li * 9 + 6]);
      }
    }
  }

  {
    const float q0 = (px + 4.f) * 0.125f;
    const float q1 = (py + 4.f) * 0.125f;
    const float q2 = (pz + 2.f) * 0.25f;
    const float* __restrict__ ht = P.hash;
#pragma unroll
    for (int l = 0; l < 16; ++l) {
      const float r = HRg[l];
      float x0 = q0 * r, x1 = q1 * r, x2 = q2 * r;
      float f0 = floorf(x0), f1 = floorf(x1), f2 = floorf(x2);
      float w0 = x0 - f0, w1 = x1 - f1, w2 = x2 - f2;
      unsigned i0 = (unsigned)(int)f0, i1 = (unsigned)(int)f1, i2 = (unsigned)(int)f2;
      float a0 = 0.f, a1 = 0.f;
#pragma unroll
      for (int dz = 0; dz < 2; ++dz)
#pragma unroll
        for (int dy = 0; dy < 2; ++dy)
#pragma unroll
          for (int dx = 0; dx < 2; ++dx) {
            unsigned h = (i0 + dx) ^ ((i1 + dy) * 2654435761u) ^ ((i2 + dz) * 805459861u);
            unsigned idx = h & 65535u;
            const float2 tv = *(const float2*)(ht + (((unsigned)l << 16) + idx) * 2);
            float wgt = (dx ? w0 : 1.f - w0) * (dy ? w1 : 1.f - w1) * (dz ? w2 : 1.f - w2);
            a0 = fmaf(tv.x, wgt, a0);
            a1 = fmaf(tv.y, wgt, a1);
          }
      feat[36 + l * 2] = a0;
      feat[36 + l * 2 + 1] = a1;
    }
  }

  float acc[64];
#pragma unroll
  for (int j = 0; j < 64; ++j) acc[j] = P.b0[j];
#pragma unroll
  for (int i = 0; i < 68; ++i) {
    const float a = feat[i];
    const float* wr = P.W0 + i * 64;
#pragma unroll
    for (int j = 0; j < 64; ++j) acc[j] = fmaf(a, wr[j], acc[j]);
  }
  float hid[64];
#pragma unroll
  for (int j = 0; j < 64; ++j) hid[j] = fmaxf(acc[j], 0.f);

#pragma unroll
  for (int j = 0; j < 64; ++j) acc[j] = P.b1[j];
#pragma unroll
  for (int i = 0; i < 64; ++i) {
    const float a = hid[i];
    const float* wr = P.W1 + i * 64;
#pragma unroll
    for (int j = 0; j < 64; ++j) acc[j] = fmaf(a, wr[j], acc[j]);
  }
#pragma unroll
  for (int j = 0; j < 64; ++j) hid[j] = fmaxf(acc[j], 0.f);

  float so[33];
#pragma unroll
  for (int j = 0; j < 33; ++j) so[j] = P.bo[j];
#pragma unroll
  for (int i = 0; i < 64; ++i) {
    const float a = hid[i];
    const float* wr = P.Wo + i * 33;
#pragma unroll
    for (int j = 0; j < 33; ++j) so[j] = fmaf(a, wr[j], so[j]);
  }
  const float sdf = my_tanh(so[0]);
  float geo[32];
#pragma unroll
  for (int j = 0; j < 32; ++j) geo[j] = my_tanh(so[j + 1]);

#pragma unroll
  for (int j = 0; j < 64; ++j) acc[j] = P.bc0[j];
#pragma unroll
  for (int i = 0; i < 32; ++i) {
    const float a = geo[i];
    const float* wr = P.Wc0 + i * 64;
#pragma unroll
    for (int j = 0; j < 64; ++j) acc[j] = fmaf(a, wr[j], acc[j]);
  }
#pragma unroll
  for (int i = 0; i < 36; ++i) {
    const float a = feat[i];
    const float* wr = P.Wc0 + (32 + i) * 64;
#pragma unroll
    for (int j = 0; j < 64; ++j) acc[j] = fmaf(a, wr[j], acc[j]);
  }
#pragma unroll
  for (int j = 0; j < 64; ++j) hid[j] = fmaxf(acc[j], 0.f);

  float c1[32];
#pragma unroll
  for (int j = 0; j < 32; ++j) c1[j] = P.bc1[j];
#pragma unroll
  for (int i = 0; i < 64; ++i) {
    const float a = hid[i];
    const float* wr = P.Wc1 + i * 32;
#pragma unroll
    for (int j = 0; j < 32; ++j) c1[j] = fmaf(a, wr[j], c1[j]);
  }

  float r0 = P.bco[0], r1 = P.bco[1], r2 = P.bco[2];
#pragma unroll
  for (int i = 0; i < 32; ++i) {
    const float a = fmaxf(c1[i], 0.f);
    r0 = fmaf(a, P.Wco[i * 3 + 0], r0);
    r1 = fmaf(a, P.Wco[i * 3 + 1], r1);
    r2 = fmaf(a, P.Wco[i * 3 + 2], r2);
  }

  float4 o;
  o.x = my_sigmoid(r0);
  o.y = my_sigmoid(r1);
  o.z = my_sigmoid(r2);
  o.w = sdf;
  ((float4*)P.out)[tid] = o;
}

// ---------------- launch ----------------

extern "C" void kernel_launch(void* const* d_in, const int* in_sizes, int n_in,
                              void* d_out, int out_size, void* d_ws, size_t ws_size,
                              hipStream_t stream) {
  const int RES[4] = {128, 256, 512, 1024};
  const size_t planes_bytes = (size_t)4177920 * 8;
  const size_t hash_bytes = (size_t)16 * 65536 * 4;
  const size_t qs_bytes = (size_t)NPTS * 16;
  const size_t hist_bytes = (size_t)NBKT * 4;
  const size_t need_fused = planes_bytes + hash_bytes + qs_bytes + 2 * hist_bytes + 4096;
  const size_t need_mid = planes_bytes + 64;

  char* wsp = (char*)d_ws;
  const float* p = (const float*)d_in[0];

  if (ws_size >= need_fused) {
    size_t off = 0;
    PrepParams PP;
    PP.p = p;
    PP.hash = (const float*)d_in[13];
    const uint2* planes = (const uint2*)wsp;
    for (int i = 0; i < 12; ++i) {
      int R = RES[i / 3];
      PP.psrc[i] = (const float*)d_in[1 + i];
      PP.pdst[i] = (ushort4*)(wsp + off);
      off += (size_t)R * R * 8;
    }
    unsigned* hashb = (unsigned*)(wsp + off);
    PP.hashb = hashb;
    off += hash_bytes;
    float4* qs = (float4*)(wsp + off);
    off += qs_bytes;
    unsigned* hist = (unsigned*)(wsp + off);
    off += hist_bytes;
    unsigned* cursor = (unsigned*)(wsp + off);
    off += hist_bytes;
    unsigned* partial = (unsigned*)(wsp + off);
    off += 1024;
    unsigned* base = (unsigned*)(wsp + off);
    off += 1024;
    PP.hist = hist;

    hipMemsetAsync(hist, 0, hist_bytes, stream);
    prep_kernel<<<PB_PLANES + PB_HASH + PB_HIST, 256, 0, stream>>>(PP);
    scan1_kernel<<<256, 256, 0, stream>>>(hist, partial);
    scan2_kernel<<<1, 256, 0, stream>>>(partial, base);
    scan3_kernel<<<256, 256, 0, stream>>>(hist, base, cursor);
    scatter_kernel<<<NPTS / 256, 256, 0, stream>>>(p, cursor, qs);

    MlpWParams MP;
    MP.planes = planes;
    MP.hashb = hashb;
    MP.qs = qs;
    MP.W0 = (const float*)d_in[14]; MP.b0 = (const float*)d_in[15];
    MP.W1 = (const float*)d_in[16]; MP.b1 = (const float*)d_in[17];
    MP.Wo = (const float*)d_in[18]; MP.bo = (const float*)d_in[19];
    MP.Wc0 = (const float*)d_in[20]; MP.bc0 = (const float*)d_in[21];
    MP.Wc1 = (const float*)d_in[22]; MP.bc1 = (const float*)d_in[23];
    MP.Wco = (const float*)d_in[24]; MP.bco = (const float*)d_in[25];
    MP.out = (float*)d_out;
    mlp_fused<<<MLP_BLOCKS, MLP_THREADS, 0, stream>>>(MP);
    return;
  }

  DecParams P;
  P.p = p;
  for (int i = 0; i < 12; ++i) P.pl[i] = (const float*)d_in[1 + i];
  P.hash = (const float*)d_in[13];
  P.W0  = (const float*)d_in[14]; P.b0  = (const float*)d_in[15];
  P.W1  = (const float*)d_in[16]; P.b1  = (const float*)d_in[17];
  P.Wo  = (const float*)d_in[18]; P.bo  = (const float*)d_in[19];
  P.Wc0 = (const float*)d_in[20]; P.bc0 = (const float*)d_in[21];
  P.Wc1 = (const float*)d_in[22]; P.bc1 = (const float*)d_in[23];
  P.Wco = (const float*)d_in[24]; P.bco = (const float*)d_in[25];
  P.out = (float*)d_out;

  if (ws_size >= need_mid) {
    size_t off = 0;
    for (int i = 0; i < 12; ++i) {
      int R = RES[i / 3];
      int n = R * R;
      P.pli[i] = (const uint2*)(wsp + off);
      repack_plane<<<(n + 255) / 256, 256, 0, stream>>>(
          (const float*)d_in[1 + i], (ushort4*)(wsp + off), R);
      off += (size_t)n * 8;
    }
    dec_kernel<true><<<NPTS / 256, 256, 0, stream>>>(P);
  } else {
    for (int i = 0; i < 12; ++i) P.pli[i] = nullptr;
    dec_kernel<false><<<NPTS / 256, 256, 0, stream>>>(P);
  }
}

// Round 14
// 376.593 us; speedup vs baseline: 1.1476x; 1.1476x over previous
//
#include <hip/hip_runtime.h>

#define NPTS 1048576
#define NBKT 262144  // 2^18 Morton buckets

typedef short bhalf8 __attribute__((ext_vector_type(8)));
typedef _Float16 halfv8 __attribute__((ext_vector_type(8)));
typedef _Float16 halfv2 __attribute__((ext_vector_type(2)));
typedef float floatx4 __attribute__((ext_vector_type(4)));

#define WSZ 24320  // f16 elements of weight storage
#define FROWS 22   // fbuf rows: 18 plane dwords + 3 q floats + pid
#define MLP_THREADS 1024
#define MLP_WAVES 16

// prep_kernel block ranges
#define PB_PLANES 16320  // 4177920 texels / 256
#define PB_HASH 4096
#define PB_HIST 4096

__device__ const float HRg[16] = {16.f, 19.f, 24.f, 30.f, 37.f, 46.f, 57.f, 71.f,
                                  89.f, 110.f, 136.f, 169.f, 210.f, 260.f, 322.f, 400.f};

// ---------------- helpers ----------------

__device__ __forceinline__ float my_tanh(float x) {
  float e = __expf(2.f * x);
  return 1.f - 2.f * __builtin_amdgcn_rcpf(e + 1.f);
}

__device__ __forceinline__ float my_sigmoid(float x) {
  return __builtin_amdgcn_rcpf(1.f + __expf(-x));
}

__device__ __forceinline__ unsigned short f2h(float v) {
  _Float16 h = (_Float16)v;
  unsigned short u;
  __builtin_memcpy(&u, &h, 2);
  return u;
}

__device__ __forceinline__ float h2f(unsigned short u) {
  _Float16 h;
  __builtin_memcpy(&h, &u, 2);
  return (float)h;
}

__device__ __forceinline__ float texch(uint2 t, int c) {
  unsigned short u = (c == 0) ? (unsigned short)(t.x & 0xffffu)
                   : (c == 1) ? (unsigned short)(t.x >> 16)
                              : (unsigned short)(t.y & 0xffffu);
  return h2f(u);
}

__device__ __forceinline__ unsigned mort6(unsigned x) {
  return (x & 1) | ((x & 2) << 2) | ((x & 4) << 4) |
         ((x & 8) << 6) | ((x & 16) << 8) | ((x & 32) << 10);
}

__device__ __forceinline__ unsigned morton_key(float px, float py, float pz) {
  float qx = (px + 4.f) * 0.125f, qy = (py + 4.f) * 0.125f, qz = (pz + 2.f) * 0.25f;
  unsigned kx = min(63, max(0, (int)(qx * 64.f)));
  unsigned ky = min(63, max(0, (int)(qy * 64.f)));
  unsigned kz = min(63, max(0, (int)(qz * 64.f)));
  return mort6(kx) | (mort6(ky) << 1) | (mort6(kz) << 2);
}

// one hash level -> packed 2xf16 pair (packed f16 interpolation)
__device__ __forceinline__ unsigned hash_level(const unsigned* __restrict__ ht, int lv,
                                               float q0, float q1, float q2) {
  const float r = HRg[lv];
  float x0 = q0 * r, x1 = q1 * r, x2 = q2 * r;
  float f0 = floorf(x0), f1 = floorf(x1), f2 = floorf(x2);
  float w0 = x0 - f0, w1 = x1 - f1, w2 = x2 - f2;
  unsigned i0 = (unsigned)(int)f0, i1 = (unsigned)(int)f1, i2 = (unsigned)(int)f2;
  const unsigned* __restrict__ hb = ht + ((unsigned)lv << 16);
  unsigned tv[8];
#pragma unroll
  for (int dz = 0; dz < 2; ++dz)
#pragma unroll
    for (int dy = 0; dy < 2; ++dy)
#pragma unroll
      for (int dx = 0; dx < 2; ++dx) {
        unsigned h = (i0 + dx) ^ ((i1 + dy) * 2654435761u) ^ ((i2 + dz) * 805459861u);
        tv[dz * 4 + dy * 2 + dx] = hb[h & 65535u];
      }
  halfv2 acc2 = {(_Float16)0.f, (_Float16)0.f};
#pragma unroll
  for (int c = 0; c < 8; ++c) {
    const int dx = c & 1, dy = (c >> 1) & 1, dz = c >> 2;
    float wgt = (dx ? w0 : 1.f - w0) * (dy ? w1 : 1.f - w1) * (dz ? w2 : 1.f - w2);
    halfv2 th;
    __builtin_memcpy(&th, &tv[c], 4);
    _Float16 wh = (_Float16)wgt;
    halfv2 w2v = {wh, wh};
    acc2 = th * w2v + acc2;
  }
  unsigned res;
  __builtin_memcpy(&res, &acc2, 4);
  return res;
}

// ---------------- fused prep kernel ----------------

struct PrepParams {
  const float* psrc[12];
  ushort4* pdst[12];
  const float* hash;
  unsigned* hashb;
  const float* p;
  unsigned* hist;
};

__global__ __launch_bounds__(256) void prep_kernel(PrepParams P) {
  const int b = blockIdx.x;
  if (b < PB_PLANES) {
    const int CUM[13] = {0, 16384, 32768, 49152, 114688, 180224, 245760,
                         507904, 770048, 1032192, 2080768, 3129344, 4177920};
    const int RESL[12] = {128, 128, 128, 256, 256, 256, 512, 512, 512, 1024, 1024, 1024};
    const int s = b << 8;
    int pi = 0;
#pragma unroll
    for (int i = 1; i < 12; ++i)
      if (s >= CUM[i]) pi = i;
    const int li = s + threadIdx.x - CUM[pi];
    const int R = RESL[pi];
    const int n = R * R;
    const float* __restrict__ src = P.psrc[pi];
    ushort4 t;
    t.x = f2h(src[li]);
    t.y = f2h(src[n + li]);
    t.z = f2h(src[2 * n + li]);
    t.w = 0;
    P.pdst[pi][li] = t;
  } else if (b < PB_PLANES + PB_HASH) {
    const int i = ((b - PB_PLANES) << 8) + threadIdx.x;
    float2 v = *(const float2*)(P.hash + (size_t)i * 2);
    P.hashb[i] = (unsigned)f2h(v.x) | ((unsigned)f2h(v.y) << 16);
  } else {
    const int i = ((b - PB_PLANES - PB_HASH) << 8) + threadIdx.x;
    const float* pp = P.p + (size_t)i * 3;
    unsigned k = morton_key(pp[0], pp[1], pp[2]);
    atomicAdd(&P.hist[k], 1u);
  }
}

// ---------------- hierarchical scan (2 kernels) ----------------

__global__ __launch_bounds__(256) void scan1_kernel(const unsigned* __restrict__ hist,
                                                    unsigned* __restrict__ partial) {
  __shared__ unsigned s[256];
  const int b = blockIdx.x, t = threadIdx.x;
  uint4 v = ((const uint4*)(hist + b * 1024))[t];
  s[t] = v.x + v.y + v.z + v.w;
  __syncthreads();
  for (int d = 128; d > 0; d >>= 1) {
    if (t < d) s[t] += s[t + d];
    __syncthreads();
  }
  if (t == 0) partial[b] = s[0];
}

// merged scan2+scan3: each block computes its base from partials, then local scan
__global__ __launch_bounds__(256) void scan23_kernel(const unsigned* __restrict__ hist,
                                                     const unsigned* __restrict__ partial,
                                                     unsigned* __restrict__ cursor) {
  __shared__ unsigned sp[256];
  __shared__ unsigned s2[256];
  const int b = blockIdx.x, t = threadIdx.x;
  sp[t] = partial[t];
  __syncthreads();
  for (int d = 1; d < 256; d <<= 1) {
    unsigned v = (t >= d) ? sp[t - d] : 0u;
    __syncthreads();
    sp[t] += v;
    __syncthreads();
  }
  const unsigned base = (b == 0) ? 0u : sp[b - 1];

  uint4 v = ((const uint4*)(hist + b * 1024))[t];
  unsigned sum = v.x + v.y + v.z + v.w;
  s2[t] = sum;
  __syncthreads();
  for (int d = 1; d < 256; d <<= 1) {
    unsigned x = (t >= d) ? s2[t - d] : 0u;
    __syncthreads();
    s2[t] += x;
    __syncthreads();
  }
  unsigned off = base + s2[t] - sum;
  uint4 c;
  c.x = off;
  c.y = off + v.x;
  c.z = off + v.x + v.y;
  c.w = off + v.x + v.y + v.z;
  ((uint4*)(cursor + b * 1024))[t] = c;
}

// scatter: write sorted {q0,q1,q2,pid} per slot
__global__ __launch_bounds__(256) void scatter_kernel(const float* __restrict__ p,
                                                      unsigned* __restrict__ cursor,
                                                      float4* __restrict__ qs) {
  int i = blockIdx.x * 256 + threadIdx.x;
  const float* pp = p + (size_t)i * 3;
  const float px = pp[0], py = pp[1], pz = pp[2];
  unsigned k = morton_key(px, py, pz);
  unsigned slot = atomicAdd(&cursor[k], 1u);
  float4 q;
  q.x = (px + 4.f) * 0.125f;
  q.y = (py + 4.f) * 0.125f;
  q.z = (pz + 2.f) * 0.25f;
  q.w = __uint_as_float((unsigned)i);
  qs[slot] = q;
}

// ---------------- repack kernel (fallback only) ----------------

__global__ __launch_bounds__(256) void repack_plane(const float* __restrict__ src,
                                                    ushort4* __restrict__ dst, int R) {
  int i = blockIdx.x * 256 + threadIdx.x;
  int n = R * R;
  if (i >= n) return;
  ushort4 t;
  t.x = f2h(src[i]);
  t.y = f2h(src[n + i]);
  t.z = f2h(src[2 * n + i]);
  t.w = 0;
  dst[i] = t;
}

// ---------------- plane samplers ----------------

__device__ __forceinline__ void sample3i(const uint2* __restrict__ pl,
                                         float a, float b, int R, float* f) {
  const float Rm1 = (float)(R - 1);
  float x = fminf(fmaxf((a + 1.f) * 0.5f * Rm1, 0.f), Rm1);
  float y = fminf(fmaxf((b + 1.f) * 0.5f * Rm1, 0.f), Rm1);
  float x0f = floorf(x), y0f = floorf(y);
  float wx = x - x0f, wy = y - y0f;
  int x0 = (int)x0f, y0 = (int)y0f;
  int x1 = min(x0 + 1, R - 1), y1 = min(y0 + 1, R - 1);
  float w00 = (1.f - wy) * (1.f - wx);
  float w01 = (1.f - wy) * wx;
  float w10 = wy * (1.f - wx);
  float w11 = wy * wx;
  uint2 t00 = pl[y0 * R + x0];
  uint2 t01 = pl[y0 * R + x1];
  uint2 t10 = pl[y1 * R + x0];
  uint2 t11 = pl[y1 * R + x1];
#pragma unroll
  for (int c = 0; c < 3; ++c) {
    f[c] = texch(t00, c) * w00 + texch(t01, c) * w01 +
           texch(t10, c) * w10 + texch(t11, c) * w11;
  }
}

__device__ __forceinline__ void sample3f(const float* __restrict__ pl,
                                         float a, float b, int R, float* f) {
  const float Rm1 = (float)(R - 1);
  float x = fminf(fmaxf((a + 1.f) * 0.5f * Rm1, 0.f), Rm1);
  float y = fminf(fmaxf((b + 1.f) * 0.5f * Rm1, 0.f), Rm1);
  float x0f = floorf(x), y0f = floorf(y);
  float wx = x - x0f, wy = y - y0f;
  int x0 = (int)x0f, y0 = (int)y0f;
  int x1 = min(x0 + 1, R - 1), y1 = min(y0 + 1, R - 1);
  float w00 = (1.f - wy) * (1.f - wx);
  float w01 = (1.f - wy) * wx;
  float w10 = wy * (1.f - wx);
  float w11 = wy * wx;
  int i00 = y0 * R + x0, i01 = y0 * R + x1;
  int i10 = y1 * R + x0, i11 = y1 * R + x1;
  const int R2 = R * R;
#pragma unroll
  for (int c = 0; c < 3; ++c) {
    const float* base = pl + c * R2;
    f[c] = base[i00] * w00 + base[i01] * w01 + base[i10] * w10 + base[i11] * w11;
  }
}

// ---------------- feature kernel (planes only, reads qs coalesced) ----------------

struct FeatParams {
  const float4* qs;
  const uint2* pli[12];
  unsigned* fbuf;
};

__global__ __launch_bounds__(256) void feat_kernel(FeatParams P) {
  int bid = blockIdx.x;
  bid = (bid & 7) * (NPTS / 256 / 8) + (bid >> 3);  // XCD-chunked (Morton octants)
  const int tid = bid * 256 + threadIdx.x;

  float4 q4 = P.qs[tid];
  const float u = 2.f * q4.x - 1.f;
  const float v = 2.f * q4.y - 1.f;
  const float w = 2.f * q4.z - 1.f;

  float pf[36];
  {
    const int RES[4] = {128, 256, 512, 1024};
#pragma unroll
    for (int li = 0; li < 4; ++li) {
      sample3i(P.pli[li * 3 + 0], u, v, RES[li], &pf[li * 9 + 0]);
      sample3i(P.pli[li * 3 + 1], u, w, RES[li], &pf[li * 9 + 3]);
      sample3i(P.pli[li * 3 + 2], v, w, RES[li], &pf[li * 9 + 6]);
    }
  }
  unsigned* __restrict__ F = P.fbuf;
#pragma unroll
  for (int kk = 0; kk < 18; ++kk) {
    unsigned pk = (unsigned)f2h(pf[2 * kk]) | ((unsigned)f2h(pf[2 * kk + 1]) << 16);
    F[(size_t)kk * NPTS + tid] = pk;
  }
  F[(size_t)18 * NPTS + tid] = __float_as_uint(q4.x);
  F[(size_t)19 * NPTS + tid] = __float_as_uint(q4.y);
  F[(size_t)20 * NPTS + tid] = __float_as_uint(q4.z);
  F[(size_t)21 * NPTS + tid] = __float_as_uint(q4.w);  // pid bits
}

// ---------------- MFMA MLP kernel (f16, operand-swapped, inline hash) ----------------

struct MlpWParams {
  const unsigned* fbuf;
  const unsigned* hashb;
  const float* W0; const float* b0;
  const float* W1; const float* b1;
  const float* Wo; const float* bo;
  const float* Wc0; const float* bc0;
  const float* Wc1; const float* bc1;
  const float* Wco; const float* bco;
  float* out;
};

__device__ __forceinline__ void stage_w(const float* __restrict__ src, int K, int Nsrc,
                                        int STR, int NPAD, int OFF, short* Wlds, int tid) {
  const int total = NPAD * STR;
  for (int idx = tid; idx < total; idx += MLP_THREADS) {
    int c = idx / STR;
    int k = idx - c * STR;
    float val = (k < K && c < Nsrc) ? src[k * Nsrc + c] : 0.f;
    Wlds[OFF + idx] = (short)f2h(val);
  }
}

__device__ __forceinline__ void stage_b(const float* __restrict__ src, int Nsrc, int NPAD,
                                        int BOFF, float* Blds, int tid) {
  for (int j = tid; j < NPAD; j += MLP_THREADS) Blds[BOFF + j] = (j < Nsrc) ? src[j] : 0.f;
}

__device__ __forceinline__ halfv8 as_h8(bhalf8 s) {
  halfv8 h;
  __builtin_memcpy(&h, &s, 16);
  return h;
}

__device__ __forceinline__ halfv8 ldA(const unsigned* __restrict__ fbuf, int pt,
                                      int kkBase, int kkLim) {
  bhalf8 r;
#pragma unroll
  for (int j = 0; j < 4; ++j) {
    const int kk = kkBase + j;
    unsigned d = 0u;
    if (kk < kkLim) d = fbuf[(size_t)kk * NPTS + pt];
    r[2 * j] = (short)(d & 0xffffu);
    r[2 * j + 1] = (short)(d >> 16);
  }
  return as_h8(r);
}

__device__ __forceinline__ halfv8 frag4(unsigned d0, unsigned d1, unsigned d2, unsigned d3) {
  bhalf8 r;
  r[0] = (short)(d0 & 0xffffu); r[1] = (short)(d0 >> 16);
  r[2] = (short)(d1 & 0xffffu); r[3] = (short)(d1 >> 16);
  r[4] = (short)(d2 & 0xffffu); r[5] = (short)(d2 >> 16);
  r[6] = (short)(d3 & 0xffffu); r[7] = (short)(d3 >> 16);
  return as_h8(r);
}

__device__ __forceinline__ halfv8 ldS(const short* scr, int rowl, int grp, int s) {
  return *(const halfv8*)&scr[rowl * 72 + 32 * s + 8 * grp];
}

// Weights as A-operand, activations as B-operand.
template <int NT, int KS, int OFF, int STR>
__device__ __forceinline__ void mlayer(const halfv8 (&af)[KS], floatx4 (&acc)[NT],
                                       const short* Wlds, int rowl, int grp) {
#pragma unroll
  for (int n = 0; n < NT; ++n) {
    floatx4 a{};
#pragma unroll
    for (int s = 0; s < KS; ++s) {
      const int wo = OFF + (16 * n + rowl) * STR + 32 * s + 8 * grp;
      const halfv8 wA = *(const halfv8*)&Wlds[wo];
      a = __builtin_amdgcn_mfma_f32_16x16x32_f16(wA, af[s], a, 0, 0, 0);
    }
    acc[n] = a;
  }
}

// D[out=16n+4grp+r][pt=rowl] -> one short4 store per tile n
template <int NT>
__device__ __forceinline__ void relu_wr(const floatx4 (&acc)[NT], const float* Blds,
                                        int boff, short* scr, int rowl, int grp) {
#pragma unroll
  for (int n = 0; n < NT; ++n) {
    const int cbase = 16 * n + 4 * grp;
    short4 v4;
    float v0 = fmaxf(acc[n][0] + Blds[boff + cbase + 0], 0.f);
    float v1 = fmaxf(acc[n][1] + Blds[boff + cbase + 1], 0.f);
    float v2 = fmaxf(acc[n][2] + Blds[boff + cbase + 2], 0.f);
    float v3 = fmaxf(acc[n][3] + Blds[boff + cbase + 3], 0.f);
    v4.x = (short)f2h(v0);
    v4.y = (short)f2h(v1);
    v4.z = (short)f2h(v2);
    v4.w = (short)f2h(v3);
    *(short4*)&scr[rowl * 72 + cbase] = v4;
  }
}

__device__ __forceinline__ void tanh_wr(const floatx4 (&acc)[3], const float* Blds,
                                        short* scr, float* ost, int rowl, int grp) {
#pragma unroll
  for (int n = 0; n < 3; ++n) {
#pragma unroll
    for (int r = 0; r < 4; ++r) {
      const int c = 16 * n + 4 * grp + r;
      float v = my_tanh(acc[n][r] + Blds[128 + c]);
      if (c == 0) ost[rowl * 4 + 3] = v;
      if (c >= 1 && c <= 32) scr[rowl * 72 + c - 1] = (short)f2h(v);
    }
  }
}

__global__ __launch_bounds__(MLP_THREADS) void mlp_mfma(MlpWParams P) {
  __shared__ short Wlds[WSZ];                      // 48,640 B (f16 weights)
  __shared__ float Blds[288];                      //  1,152 B
  __shared__ short Scr[MLP_WAVES * 16 * 72];       // 36,864 B
  __shared__ float Ost[MLP_WAVES][16][4];          //  4,096 B

  const int tid = threadIdx.x;

  stage_w(P.W0,  68, 64, 104, 64,     0, Wlds, tid);
  stage_w(P.W1,  64, 64,  72, 64,  6656, Wlds, tid);
  stage_w(P.Wo,  64, 33,  72, 48, 11264, Wlds, tid);
  stage_w(P.Wc0, 68, 64, 104, 64, 14720, Wlds, tid);
  stage_w(P.Wc1, 64, 32,  72, 32, 21376, Wlds, tid);
  stage_w(P.Wco, 32,  3,  40, 16, 23680, Wlds, tid);
  stage_b(P.b0,  64, 64,   0, Blds, tid);
  stage_b(P.b1,  64, 64,  64, Blds, tid);
  stage_b(P.bo,  33, 48, 128, Blds, tid);
  stage_b(P.bc0, 64, 64, 176, Blds, tid);
  stage_b(P.bc1, 32, 32, 240, Blds, tid);
  stage_b(P.bco,  3, 16, 272, Blds, tid);
  __syncthreads();

  const int wave = tid >> 6, lane = tid & 63;
  const int rowl = lane & 15, grp = lane >> 4;
  short* scr0 = &Scr[wave * 16 * 72];
  float* ost0 = &Ost[wave][0][0];

  const int lv0 = (grp == 0) ? 0 : (4 * grp - 2);

  int bid = blockIdx.x;
  bid = (bid & 7) * 64 + (bid >> 3);  // 512 blocks, bijective XCD chunking

  for (int t = 0; t < 8; ++t) {
    const int wbase = ((bid * 8 + t) * MLP_WAVES + wave) * 16;
    const int ptA = wbase + rowl;

    halfv8 af0A;          // fbuf dwords 4grp..4grp+3 (reused by Lc0)
    unsigned pA16, pA17;  // fbuf dwords 16,17 (reused by Lc0, grp0)
    unsigned pid;

    // ---- L0: planes (fbuf) + hash (computed in-lane) ----
    {
      const unsigned* __restrict__ F = P.fbuf;
      float qA0 = __uint_as_float(F[(size_t)18 * NPTS + ptA]);
      float qA1 = __uint_as_float(F[(size_t)19 * NPTS + ptA]);
      float qA2 = __uint_as_float(F[(size_t)20 * NPTS + ptA]);
      pid = F[(size_t)21 * NPTS + ptA];

      unsigned hA0, hA1, hA2, hA3;
      {
        const int l0 = lv0, l1 = lv0 + 1;
        const int l2 = (grp == 0) ? 14 : (lv0 + 2);
        const int l3 = (grp == 0) ? 15 : (lv0 + 3);
        hA0 = hash_level(P.hashb, l0, qA0, qA1, qA2);
        hA1 = hash_level(P.hashb, l1, qA0, qA1, qA2);
        hA2 = hash_level(P.hashb, l2, qA0, qA1, qA2);
        hA3 = hash_level(P.hashb, l3, qA0, qA1, qA2);
      }

      pA16 = F[(size_t)16 * NPTS + ptA];
      pA17 = F[(size_t)17 * NPTS + ptA];

      halfv8 s1A = (grp == 0) ? frag4(pA16, pA17, hA0, hA1) : frag4(hA0, hA1, hA2, hA3);
      halfv8 s2A = (grp == 0) ? frag4(hA2, hA3, 0u, 0u) : frag4(0u, 0u, 0u, 0u);

      af0A = ldA(P.fbuf, ptA, 4 * grp, 18);
      halfv8 afA[3] = {af0A, s1A, s2A};
      floatx4 accA[4];
      mlayer<4, 3, 0, 104>(afA, accA, Wlds, rowl, grp);
      relu_wr<4>(accA, Blds, 0, scr0, rowl, grp);
    }
    // ---- L1 ----
    {
      halfv8 afA[2] = {ldS(scr0, rowl, grp, 0), ldS(scr0, rowl, grp, 1)};
      floatx4 accA[4];
      mlayer<4, 2, 6656, 72>(afA, accA, Wlds, rowl, grp);
      relu_wr<4>(accA, Blds, 64, scr0, rowl, grp);
    }
    // ---- Lo ----
    {
      halfv8 afA[2] = {ldS(scr0, rowl, grp, 0), ldS(scr0, rowl, grp, 1)};
      floatx4 accA[3];
      mlayer<3, 2, 11264, 72>(afA, accA, Wlds, rowl, grp);
      tanh_wr(accA, Blds, scr0, ost0, rowl, grp);
    }
    // ---- Lc0 (reuse L0's fbuf fragments) ----
    {
      halfv8 s2 = (grp == 0) ? frag4(pA16, pA17, 0u, 0u) : frag4(0u, 0u, 0u, 0u);
      halfv8 afA[3] = {ldS(scr0, rowl, grp, 0), af0A, s2};
      floatx4 accA[4];
      mlayer<4, 3, 14720, 104>(afA, accA, Wlds, rowl, grp);
      relu_wr<4>(accA, Blds, 176, scr0, rowl, grp);
    }
    // ---- Lc1 ----
    {
      halfv8 afA[2] = {ldS(scr0, rowl, grp, 0), ldS(scr0, rowl, grp, 1)};
      floatx4 accA[2];
      mlayer<2, 2, 21376, 72>(afA, accA, Wlds, rowl, grp);
      relu_wr<2>(accA, Blds, 240, scr0, rowl, grp);
    }
    // ---- Lco ----
    {
      halfv8 afA[1] = {ldS(scr0, rowl, grp, 0)};
      floatx4 accA[1];
      mlayer<1, 1, 23680, 40>(afA, accA, Wlds, rowl, grp);
#pragma unroll
      for (int r = 0; r < 4; ++r) {
        const int c = 4 * grp + r;
        if (c < 3) {
          float vA = my_sigmoid(accA[0][r] + Blds[272 + c]);
          ost0[rowl * 4 + c] = vA;
        }
      }
    }

    // ---- store 16 points (lane<16 => rowl==lane, own pid valid) ----
    if (lane < 16) {
      float4 o = *(float4*)&Ost[wave][lane][0];
      ((float4*)P.out)[pid] = o;
    }
  }
}

// ---------------- fused fallback (scalar f16 kernel) ----------------

struct DecParams {
  const float* p;
  const float* pl[12];
  const uint2* pli[12];
  const float* hash;
  const float* W0; const float* b0;
  const float* W1; const float* b1;
  const float* Wo; const float* bo;
  const float* Wc0; const float* bc0;
  const float* Wc1; const float* bc1;
  const float* Wco; const float* bco;
  float* out;
};

template <bool ILV>
__global__ __launch_bounds__(256) void dec_kernel(DecParams P) {
  const int tid = blockIdx.x * 256 + threadIdx.x;

  const float* __restrict__ pp = P.p + (size_t)tid * 3;
  const float px = pp[0], py = pp[1], pz = pp[2];

  const float u = (px + 4.f) * 0.25f - 1.f;
  const float v = (py + 4.f) * 0.25f - 1.f;
  const float w = (pz + 2.f) * 0.5f - 1.f;

  float feat[68];
  {
    const int RES[4] = {128, 256, 512, 1024};
#pragma unroll
    for (int li = 0; li < 4; ++li) {
      if (ILV) {
        sample3i(P.pli[li * 3 + 0], u, v, RES[li], &feat[li * 9 + 0]);
        sample3i(P.pli[li * 3 + 1], u, w, RES[li], &feat[li * 9 + 3]);
        sample3i(P.pli[li * 3 + 2], v, w, RES[li], &feat[li * 9 + 6]);
      } else {
        sample3f(P.pl[li * 3 + 0], u, v, RES[li], &feat[li * 9 + 0]);
        sample3f(P.pl[li * 3 + 1], u, w, RES[li], &feat[li * 9 + 3]);
        sample3f(P.pl[li * 3 + 2], v, w, RES[li], &feat[li * 9 + 6]);
      }
    }
  }

  {
    const float q0 = (px + 4.f) * 0.125f;
    const float q1 = (py + 4.f) * 0.125f;
    const float q2 = (pz + 2.f) * 0.25f;
    const float* __restrict__ ht = P.hash;
#pragma unroll
    for (int l = 0; l < 16; ++l) {
      const float r = HRg[l];
      float x0 = q0 * r, x1 = q1 * r, x2 = q2 * r;
      float f0 = floorf(x0), f1 = floorf(x1), f2 = floorf(x2);
      float w0 = x0 - f0, w1 = x1 - f1, w2 = x2 - f2;
      unsigned i0 = (unsigned)(int)f0, i1 = (unsigned)(int)f1, i2 = (unsigned)(int)f2;
      float a0 = 0.f, a1 = 0.f;
#pragma unroll
      for (int dz = 0; dz < 2; ++dz)
#pragma unroll
        for (int dy = 0; dy < 2; ++dy)
#pragma unroll
          for (int dx = 0; dx < 2; ++dx) {
            unsigned h = (i0 + dx) ^ ((i1 + dy) * 2654435761u) ^ ((i2 + dz) * 805459861u);
            unsigned idx = h & 65535u;
            const float2 tv = *(const float2*)(ht + (((unsigned)l << 16) + idx) * 2);
            float wgt = (dx ? w0 : 1.f - w0) * (dy ? w1 : 1.f - w1) * (dz ? w2 : 1.f - w2);
            a0 = fmaf(tv.x, wgt, a0);
            a1 = fmaf(tv.y, wgt, a1);
          }
      feat[36 + l * 2] = a0;
      feat[36 + l * 2 + 1] = a1;
    }
  }

  float acc[64];
#pragma unroll
  for (int j = 0; j < 64; ++j) acc[j] = P.b0[j];
#pragma unroll
  for (int i = 0; i < 68; ++i) {
    const float a = feat[i];
    const float* wr = P.W0 + i * 64;
#pragma unroll
    for (int j = 0; j < 64; ++j) acc[j] = fmaf(a, wr[j], acc[j]);
  }
  float hid[64];
#pragma unroll
  for (int j = 0; j < 64; ++j) hid[j] = fmaxf(acc[j], 0.f);

#pragma unroll
  for (int j = 0; j < 64; ++j) acc[j] = P.b1[j];
#pragma unroll
  for (int i = 0; i < 64; ++i) {
    const float a = hid[i];
    const float* wr = P.W1 + i * 64;
#pragma unroll
    for (int j = 0; j < 64; ++j) acc[j] = fmaf(a, wr[j], acc[j]);
  }
#pragma unroll
  for (int j = 0; j < 64; ++j) hid[j] = fmaxf(acc[j], 0.f);

  float so[33];
#pragma unroll
  for (int j = 0; j < 33; ++j) so[j] = P.bo[j];
#pragma unroll
  for (int i = 0; i < 64; ++i) {
    const float a = hid[i];
    const float* wr = P.Wo + i * 33;
#pragma unroll
    for (int j = 0; j < 33; ++j) so[j] = fmaf(a, wr[j], so[j]);
  }
  const float sdf = my_tanh(so[0]);
  float geo[32];
#pragma unroll
  for (int j = 0; j < 32; ++j) geo[j] = my_tanh(so[j + 1]);

#pragma unroll
  for (int j = 0; j < 64; ++j) acc[j] = P.bc0[j];
#pragma unroll
  for (int i = 0; i < 32; ++i) {
    const float a = geo[i];
    const float* wr = P.Wc0 + i * 64;
#pragma unroll
    for (int j = 0; j < 64; ++j) acc[j] = fmaf(a, wr[j], acc[j]);
  }
#pragma unroll
  for (int i = 0; i < 36; ++i) {
    const float a = feat[i];
    const float* wr = P.Wc0 + (32 + i) * 64;
#pragma unroll
    for (int j = 0; j < 64; ++j) acc[j] = fmaf(a, wr[j], acc[j]);
  }
#pragma unroll
  for (int j = 0; j < 64; ++j) hid[j] = fmaxf(acc[j], 0.f);

  float c1[32];
#pragma unroll
  for (int j = 0; j < 32; ++j) c1[j] = P.bc1[j];
#pragma unroll
  for (int i = 0; i < 64; ++i) {
    const float a = hid[i];
    const float* wr = P.Wc1 + i * 32;
#pragma unroll
    for (int j = 0; j < 32; ++j) c1[j] = fmaf(a, wr[j], c1[j]);
  }

  float r0 = P.bco[0], r1 = P.bco[1], r2 = P.bco[2];
#pragma unroll
  for (int i = 0; i < 32; ++i) {
    const float a = fmaxf(c1[i], 0.f);
    r0 = fmaf(a, P.Wco[i * 3 + 0], r0);
    r1 = fmaf(a, P.Wco[i * 3 + 1], r1);
    r2 = fmaf(a, P.Wco[i * 3 + 2], r2);
  }

  float4 o;
  o.x = my_sigmoid(r0);
  o.y = my_sigmoid(r1);
  o.z = my_sigmoid(r2);
  o.w = sdf;
  ((float4*)P.out)[tid] = o;
}

// ---------------- launch ----------------

extern "C" void kernel_launch(void* const* d_in, const int* in_sizes, int n_in,
                              void* d_out, int out_size, void* d_ws, size_t ws_size,
                              hipStream_t stream) {
  const int RES[4] = {128, 256, 512, 1024};
  const size_t planes_bytes = (size_t)4177920 * 8;
  const size_t hash_bytes = (size_t)16 * 65536 * 4;
  const size_t feat_bytes = (size_t)FROWS * NPTS * 4;
  const size_t qs_bytes = (size_t)NPTS * 16;
  const size_t hist_bytes = (size_t)NBKT * 4;
  const size_t need_sort = planes_bytes + hash_bytes + feat_bytes + qs_bytes +
                           2 * hist_bytes + 4096;
  const size_t need_mid = planes_bytes + 64;

  char* wsp = (char*)d_ws;
  const float* p = (const float*)d_in[0];

  if (ws_size >= need_sort) {
    size_t off = 0;
    PrepParams PP;
    PP.p = p;
    PP.hash = (const float*)d_in[13];
    const uint2* pli[12];
    for (int i = 0; i < 12; ++i) {
      int R = RES[i / 3];
      PP.psrc[i] = (const float*)d_in[1 + i];
      PP.pdst[i] = (ushort4*)(wsp + off);
      pli[i] = (const uint2*)(wsp + off);
      off += (size_t)R * R * 8;
    }
    unsigned* hashb = (unsigned*)(wsp + off);
    PP.hashb = hashb;
    off += hash_bytes;
    unsigned* fbuf = (unsigned*)(wsp + off);
    off += feat_bytes;
    float4* qs = (float4*)(wsp + off);
    off += qs_bytes;
    unsigned* hist = (unsigned*)(wsp + off);
    off += hist_bytes;
    unsigned* cursor = (unsigned*)(wsp + off);
    off += hist_bytes;
    unsigned* partial = (unsigned*)(wsp + off);
    off += 2048;
    PP.hist = hist;

    hipMemsetAsync(hist, 0, hist_bytes, stream);
    prep_kernel<<<PB_PLANES + PB_HASH + PB_HIST, 256, 0, stream>>>(PP);
    scan1_kernel<<<256, 256, 0, stream>>>(hist, partial);
    scan23_kernel<<<256, 256, 0, stream>>>(hist, partial, cursor);
    scatter_kernel<<<NPTS / 256, 256, 0, stream>>>(p, cursor, qs);

    FeatParams FP;
    FP.qs = qs;
    for (int i = 0; i < 12; ++i) FP.pli[i] = pli[i];
    FP.fbuf = fbuf;
    feat_kernel<<<NPTS / 256, 256, 0, stream>>>(FP);

    MlpWParams MP;
    MP.fbuf = fbuf;
    MP.hashb = hashb;
    MP.W0 = (const float*)d_in[14]; MP.b0 = (const float*)d_in[15];
    MP.W1 = (const float*)d_in[16]; MP.b1 = (const float*)d_in[17];
    MP.Wo = (const float*)d_in[18]; MP.bo = (const float*)d_in[19];
    MP.Wc0 = (const float*)d_in[20]; MP.bc0 = (const float*)d_in[21];
    MP.Wc1 = (const float*)d_in[22]; MP.bc1 = (const float*)d_in[23];
    MP.Wco = (const float*)d_in[24]; MP.bco = (const float*)d_in[25];
    MP.out = (float*)d_out;
    mlp_mfma<<<512, MLP_THREADS, 0, stream>>>(MP);
    return;
  }

  DecParams P;
  P.p = p;
  for (int i = 0; i < 12; ++i) P.pl[i] = (const float*)d_in[1 + i];
  P.hash = (const float*)d_in[13];
  P.W0  = (const float*)d_in[14]; P.b0  = (const float*)d_in[15];
  P.W1  = (const float*)d_in[16]; P.b1  = (const float*)d_in[17];
  P.Wo  = (const float*)d_in[18]; P.bo  = (const float*)d_in[19];
  P.Wc0 = (const float*)d_in[20]; P.bc0 = (const float*)d_in[21];
  P.Wc1 = (const float*)d_in[22]; P.bc1 = (const float*)d_in[23];
  P.Wco = (const float*)d_in[24]; P.bco = (const float*)d_in[25];
  P.out = (float*)d_out;

  if (ws_size >= need_mid) {
    size_t off = 0;
    for (int i = 0; i < 12; ++i) {
      int R = RES[i / 3];
      int n = R * R;
      P.pli[i] = (const uint2*)(wsp + off);
      repack_plane<<<(n + 255) / 256, 256, 0, stream>>>(
          (const float*)d_in[1 + i], (ushort4*)(wsp + off), R);
      off += (size_t)n * 8;
    }
    dec_kernel<true><<<NPTS / 256, 256, 0, stream>>>(P);
  } else {
    for (int i = 0; i < 12; ++i) P.pli[i] = nullptr;
    dec_kernel<false><<<NPTS / 256, 256, 0, stream>>>(P);
  }
}